// Round 5
// baseline (530.099 us; speedup 1.0000x reference)
//
#include <hip/hip_runtime.h>
#include <math.h>

typedef float v4f __attribute__((ext_vector_type(4)));

// x: [B=16, C=2048, H=64, W=64] fp32. H*W = 4096 contiguous floats per channel.
// Fused kernel: 2048 blocks x 256 threads. Pool phase identical to R2 best
// (one wave per channel group, 2 batches of 8 float4 NT loads, shuffle reduce).
// Batch b's channels (b*2048..b*2048+2047) are produced exactly by blocks
// [128b, 128b+128). Each block signals completion via device-scope atomicAdd
// on counters[b] (after __threadfence release-flush); the 128th block acquires
// (__threadfence -> L2 invalidate, needed across XCDs) and runs batch b's SE
// inline -- overlapping SE with other batches' pool streaming.
__global__ __launch_bounds__(256) void fused_kernel(const float* __restrict__ x,
                                                    const float* __restrict__ w_ch,
                                                    const float* __restrict__ w1,
                                                    const float* __restrict__ w2,
                                                    float* __restrict__ out,
                                                    float* __restrict__ mean_ws,
                                                    float* __restrict__ max_ws,
                                                    unsigned int* __restrict__ counters) {
    const int wave = threadIdx.x >> 6;
    const int lane = threadIdx.x & 63;
    const int wave_g = (blockIdx.x << 2) + wave;     // 0..8191

    // ---- pool phase (R2-best structure) ----
#pragma unroll 1
    for (int i = 0; i < 4; ++i) {
        const int bc = (wave_g << 2) + i;            // 0..32767 (b*2048 + c)
        const v4f* p4 = (const v4f*)(x + (size_t)bc * 4096);

        float s = 0.f;
        float m = -INFINITY;
#pragma unroll 1
        for (int batch = 0; batch < 2; ++batch) {
            v4f v[8];
#pragma unroll
            for (int j = 0; j < 8; ++j)
                v[j] = __builtin_nontemporal_load(&p4[lane + (batch * 8 + j) * 64]);
#pragma unroll
            for (int j = 0; j < 8; ++j) {
                s += (v[j].x + v[j].y) + (v[j].z + v[j].w);
                m = fmaxf(m, fmaxf(fmaxf(v[j].x, v[j].y), fmaxf(v[j].z, v[j].w)));
            }
        }
#pragma unroll
        for (int off = 32; off > 0; off >>= 1) {
            s += __shfl_down(s, off, 64);
            m = fmaxf(m, __shfl_down(m, off, 64));
        }
        if (lane == 0) {
            mean_ws[bc] = s * (1.0f / 4096.0f);
            max_ws[bc]  = m;
        }
    }

    // ---- completion signal for this block's batch ----
    const int b = blockIdx.x >> 7;                   // blockIdx / 128 = batch
    __threadfence();                                 // release: flush our stores
    __syncthreads();                                 // all waves fenced
    __shared__ unsigned int old_cnt;
    if (threadIdx.x == 0)
        old_cnt = atomicAdd(&counters[b], 1u);       // device-scope by default
    __syncthreads();
    if (old_cnt != 127u) return;

    // ---- last block of batch b: SE branch ----
    __threadfence();                                 // acquire: invalidate stale L1/L2
    const int tid = threadIdx.x;
    __shared__ float fa[256];
    __shared__ float fm[256];
    __shared__ float hs[128];
    __shared__ float wc[8];
    if (tid < 8) wc[tid] = w_ch[tid];
    __syncthreads();

    {   // orientation contraction: each thread owns one k
        const float* pa = mean_ws + b * 2048 + tid * 8;
        const float* pm = max_ws  + b * 2048 + tid * 8;
        float sa = 0.f, sx = 0.f;
#pragma unroll
        for (int o = 0; o < 8; ++o) {
            sa += pa[o] * wc[o];
            sx += pm[o] * wc[o];
        }
        fa[tid] = sa;
        fm[tid] = sx;
    }
    __syncthreads();

    if (tid < 128) {                 // first matvec, both branches share w1 read
        const float* w1r = w1 + tid * 256;
        float sa = 0.f, sx = 0.f;
        for (int k = 0; k < 256; ++k) {
            float w = w1r[k];
            sa += fa[k] * w;
            sx += fm[k] * w;
        }
        hs[tid] = fmaxf(sa, 0.f) + fmaxf(sx, 0.f);   // w2 linear -> relu-sum ok
    }
    __syncthreads();

    {   // second matvec + sigmoid + 8-way repeat
        const float* w2r = w2 + tid * 128;
        float s = 0.f;
        for (int j = 0; j < 128; ++j) s += hs[j] * w2r[j];
        float y = 1.0f / (1.0f + expf(-s));
        float4 v = make_float4(y, y, y, y);
        float4* o4 = (float4*)(out + b * 2048 + tid * 8);
        o4[0] = v;
        o4[1] = v;
    }
}

extern "C" void kernel_launch(void* const* d_in, const int* in_sizes, int n_in,
                              void* d_out, int out_size, void* d_ws, size_t ws_size,
                              hipStream_t stream) {
    const float* x    = (const float*)d_in[0];   // [16,2048,64,64]
    const float* w_ch = (const float*)d_in[1];   // [8]
    const float* w1   = (const float*)d_in[2];   // [128,256]
    const float* w2   = (const float*)d_in[3];   // [256,128]
    float* out = (float*)d_out;                  // [16,2048] (as [B,C,1,1])

    float* mean_ws = (float*)d_ws;               // 32768 floats
    float* max_ws  = mean_ws + 32768;            // 32768 floats
    unsigned int* counters = (unsigned int*)(max_ws + 32768);  // 16 u32

    hipMemsetAsync(counters, 0, 16 * sizeof(unsigned int), stream);
    fused_kernel<<<2048, 256, 0, stream>>>(x, w_ch, w1, w2, out,
                                           mean_ws, max_ws, counters);
}

// Round 6
// 115.256 us; speedup vs baseline: 4.5993x; 4.5993x over previous
//
#include <hip/hip_runtime.h>
#include <math.h>

typedef float v4f __attribute__((ext_vector_type(4)));

// x: [B=16, C=2048, H=64, W=64] fp32. H*W = 4096 contiguous floats per channel.
// Pool kernel: 2048 blocks x 256 threads, one wave per 4 consecutive channels
// (wave-contiguous 64 KB stream). Explicit double-buffered pipeline: 16 steps
// of 4 float4 loads; next batch is always issued BEFORE consuming the current
// one, so the wave keeps 4-8 loads in flight continuously (no vmcnt-drain
// bubble between batches). Live regs ~50 -> full 8 blocks/CU occupancy.
// Channel c (0..3) owns steps 4c..4c+3; per-channel accumulators; 4 butterfly
// reduces at the end. No LDS, no barriers.
__global__ __launch_bounds__(256) void pool_kernel(const float* __restrict__ x,
                                                   float* __restrict__ mean_out,
                                                   float* __restrict__ max_out) {
    const int wave_g = (blockIdx.x << 2) + (threadIdx.x >> 6);   // 0..8191
    const int lane = threadIdx.x & 63;
    const v4f* base = (const v4f*)(x + ((size_t)wave_g << 14));  // 4 ch * 4096 f

    float s[4], m[4];
#pragma unroll
    for (int c = 0; c < 4; ++c) { s[c] = 0.f; m[c] = -INFINITY; }

    v4f A[4], B[4];
    // prologue: step 0 into A
#pragma unroll
    for (int k = 0; k < 4; ++k) A[k] = base[(k << 6) + lane];

#pragma unroll
    for (int st2 = 0; st2 < 8; ++st2) {
        const int s0 = st2 * 2;          // even step (in A)
        const int s1 = s0 + 1;           // odd step  (in B)
        // issue odd step into B, then consume A
#pragma unroll
        for (int k = 0; k < 4; ++k) B[k] = base[(s1 << 8) + (k << 6) + lane];
#pragma unroll
        for (int k = 0; k < 4; ++k) {
            const v4f v = A[k];
            s[s0 >> 2] += (v.x + v.y) + (v.z + v.w);
            m[s0 >> 2] = fmaxf(m[s0 >> 2],
                               fmaxf(fmaxf(v.x, v.y), fmaxf(v.z, v.w)));
        }
        // issue next even step into A, then consume B
        if (st2 < 7) {
#pragma unroll
            for (int k = 0; k < 4; ++k) A[k] = base[((s0 + 2) << 8) + (k << 6) + lane];
        }
#pragma unroll
        for (int k = 0; k < 4; ++k) {
            const v4f v = B[k];
            s[s1 >> 2] += (v.x + v.y) + (v.z + v.w);
            m[s1 >> 2] = fmaxf(m[s1 >> 2],
                               fmaxf(fmaxf(v.x, v.y), fmaxf(v.z, v.w)));
        }
    }

    // 4 independent wave64 butterfly reduces (interleaved chains)
#pragma unroll
    for (int off = 32; off > 0; off >>= 1) {
#pragma unroll
        for (int c = 0; c < 4; ++c) {
            s[c] += __shfl_down(s[c], off, 64);
            m[c] = fmaxf(m[c], __shfl_down(m[c], off, 64));
        }
    }
    if (lane == 0) {
        const int bc0 = wave_g << 2;
#pragma unroll
        for (int c = 0; c < 4; ++c) {
            mean_out[bc0 + c] = s[c] * (1.0f / 4096.0f);
            max_out[bc0 + c]  = m[c];
        }
    }
}

// Kernel 2: SE branch. One block per batch element, 16 blocks x 256 threads.
// f[k]   = sum_o pooled[b][k*8+o] * w_ch[o]
// h[j]   = relu(<f_avg, w1[j]>) + relu(<f_max, w1[j]>)   (w2 linear -> sum ok)
// y[k]   = sigmoid(<h, w2[k]>) ; out[b][k*8+o] = y[k]
// First matvec uses ALL 256 threads: waves 0-1 avg branch, waves 2-3 max branch
// (wave-uniform select, w1 rows L1-hit for the second half). float4 weight
// loads; LDS reads are same-address broadcasts (conflict-free).
__global__ __launch_bounds__(256) void se_kernel(const float* __restrict__ mean_in,
                                                 const float* __restrict__ max_in,
                                                 const float* __restrict__ w_ch,
                                                 const float* __restrict__ w1,
                                                 const float* __restrict__ w2,
                                                 float* __restrict__ out) {
    const int b = blockIdx.x;        // 0..15
    const int tid = threadIdx.x;     // 0..255

    __shared__ float fa[256];
    __shared__ float fm[256];
    __shared__ float ha[128];
    __shared__ float hb[128];
    __shared__ float wc[8];
    if (tid < 8) wc[tid] = w_ch[tid];
    __syncthreads();

    {   // orientation contraction: thread tid owns k=tid, vectorized loads
        const v4f* pa = (const v4f*)(mean_in + b * 2048 + tid * 8);
        const v4f* pm = (const v4f*)(max_in  + b * 2048 + tid * 8);
        const v4f a0 = pa[0], a1 = pa[1], m0 = pm[0], m1 = pm[1];
        fa[tid] = a0.x * wc[0] + a0.y * wc[1] + a0.z * wc[2] + a0.w * wc[3]
                + a1.x * wc[4] + a1.y * wc[5] + a1.z * wc[6] + a1.w * wc[7];
        fm[tid] = m0.x * wc[0] + m0.y * wc[1] + m0.z * wc[2] + m0.w * wc[3]
                + m1.x * wc[4] + m1.y * wc[5] + m1.z * wc[6] + m1.w * wc[7];
    }
    __syncthreads();

    {   // first matvec: j = tid&127; avg branch (tid<128) or max branch
        const int j = tid & 127;
        const float* f = (tid < 128) ? fa : fm;     // wave-uniform
        const v4f* w1r = (const v4f*)(w1 + j * 256);
        float sacc = 0.f;
#pragma unroll 4
        for (int k4 = 0; k4 < 64; ++k4) {
            const v4f w = w1r[k4];
            sacc += w.x * f[k4 * 4 + 0] + w.y * f[k4 * 4 + 1]
                  + w.z * f[k4 * 4 + 2] + w.w * f[k4 * 4 + 3];
        }
        if (tid < 128) ha[j] = fmaxf(sacc, 0.f);
        else           hb[j] = fmaxf(sacc, 0.f);
    }
    __syncthreads();

    {   // second matvec + sigmoid + 8-way repeat; k = tid
        const v4f* w2r = (const v4f*)(w2 + tid * 128);
        float sacc = 0.f;
#pragma unroll 4
        for (int j4 = 0; j4 < 32; ++j4) {
            const v4f w = w2r[j4];
            sacc += w.x * (ha[j4 * 4 + 0] + hb[j4 * 4 + 0])
                  + w.y * (ha[j4 * 4 + 1] + hb[j4 * 4 + 1])
                  + w.z * (ha[j4 * 4 + 2] + hb[j4 * 4 + 2])
                  + w.w * (ha[j4 * 4 + 3] + hb[j4 * 4 + 3]);
        }
        const float y = 1.0f / (1.0f + expf(-sacc));
        const float4 v = make_float4(y, y, y, y);
        float4* o4 = (float4*)(out + b * 2048 + tid * 8);
        o4[0] = v;
        o4[1] = v;
    }
}

extern "C" void kernel_launch(void* const* d_in, const int* in_sizes, int n_in,
                              void* d_out, int out_size, void* d_ws, size_t ws_size,
                              hipStream_t stream) {
    const float* x    = (const float*)d_in[0];   // [16,2048,64,64]
    const float* w_ch = (const float*)d_in[1];   // [8]
    const float* w1   = (const float*)d_in[2];   // [128,256]
    const float* w2   = (const float*)d_in[3];   // [256,128]
    float* out = (float*)d_out;                  // [16,2048] (as [B,C,1,1])

    float* mean_ws = (float*)d_ws;               // 32768 floats
    float* max_ws  = mean_ws + 32768;            // 32768 floats

    pool_kernel<<<2048, 256, 0, stream>>>(x, mean_ws, max_ws);
    se_kernel<<<16, 256, 0, stream>>>(mean_ws, max_ws, w_ch, w1, w2, out);
}

// Round 7
// 111.814 us; speedup vs baseline: 4.7409x; 1.0308x over previous
//
#include <hip/hip_runtime.h>
#include <math.h>

typedef float v4f __attribute__((ext_vector_type(4)));

// x: [B=16, C=2048, H=64, W=64] fp32. H*W = 4096 contiguous floats per channel.
// Pool kernel: 2048 blocks x 256 threads (8 blocks/CU, exactly one round).
// One wave per 4 consecutive channels (64 KB contiguous stream per wave).
// Channel-PARALLEL accumulation: each step loads one float4 from each of the
// 4 channels (4 independent loads, 4 independent FP chains); flat 16-step loop
// with unroll 2 -> ~8 loads in flight, ~56 live VGPRs, full occupancy. The
// compiler schedules the pipeline (manual buffering regressed, R5). NT loads
// (streaming, x > L3). Butterfly reduces batched at the end; no LDS/barriers.
__global__ __launch_bounds__(256) void pool_kernel(const float* __restrict__ x,
                                                   float* __restrict__ mean_out,
                                                   float* __restrict__ max_out) {
    const int wave_g = (blockIdx.x << 2) + (threadIdx.x >> 6);   // 0..8191
    const int lane = threadIdx.x & 63;
    const v4f* base = (const v4f*)(x + ((size_t)wave_g << 14));  // 4ch * 4096 f

    float s[4], m[4];
#pragma unroll
    for (int c = 0; c < 4; ++c) { s[c] = 0.f; m[c] = -INFINITY; }

#pragma unroll 2
    for (int i = 0; i < 16; ++i) {
        v4f v[4];
#pragma unroll
        for (int c = 0; c < 4; ++c)
            v[c] = __builtin_nontemporal_load(&base[(c << 10) + (i << 6) + lane]);
#pragma unroll
        for (int c = 0; c < 4; ++c) {
            s[c] += (v[c].x + v[c].y) + (v[c].z + v[c].w);
            m[c] = fmaxf(m[c], fmaxf(fmaxf(v[c].x, v[c].y), fmaxf(v[c].z, v[c].w)));
        }
    }

    // 4 independent wave64 butterfly reduces (interleaved shuffle chains)
#pragma unroll
    for (int off = 32; off > 0; off >>= 1) {
#pragma unroll
        for (int c = 0; c < 4; ++c) {
            s[c] += __shfl_down(s[c], off, 64);
            m[c] = fmaxf(m[c], __shfl_down(m[c], off, 64));
        }
    }
    if (lane == 0) {
        const int bc0 = wave_g << 2;
#pragma unroll
        for (int c = 0; c < 4; ++c) {
            mean_out[bc0 + c] = s[c] * (1.0f / 4096.0f);
            max_out[bc0 + c]  = m[c];
        }
    }
}

// Kernel 2: SE branch. One block per batch element, 16 blocks x 256 threads.
// f[k]   = sum_o pooled[b][k*8+o] * w_ch[o]
// h[j]   = relu(<f_avg, w1[j]>) + relu(<f_max, w1[j]>)   (w2 linear -> sum ok)
// y[k]   = sigmoid(<h, w2[k]>) ; out[b][k*8+o] = y[k]
// First matvec uses all 256 threads (waves 0-1 avg, waves 2-3 max; wave-uniform
// select). float4 weight loads; LDS reads are same-address broadcasts.
__global__ __launch_bounds__(256) void se_kernel(const float* __restrict__ mean_in,
                                                 const float* __restrict__ max_in,
                                                 const float* __restrict__ w_ch,
                                                 const float* __restrict__ w1,
                                                 const float* __restrict__ w2,
                                                 float* __restrict__ out) {
    const int b = blockIdx.x;        // 0..15
    const int tid = threadIdx.x;     // 0..255

    __shared__ float fa[256];
    __shared__ float fm[256];
    __shared__ float ha[128];
    __shared__ float hb[128];
    __shared__ float wc[8];
    if (tid < 8) wc[tid] = w_ch[tid];
    __syncthreads();

    {   // orientation contraction: thread tid owns k=tid, vectorized loads
        const v4f* pa = (const v4f*)(mean_in + b * 2048 + tid * 8);
        const v4f* pm = (const v4f*)(max_in  + b * 2048 + tid * 8);
        const v4f a0 = pa[0], a1 = pa[1], m0 = pm[0], m1 = pm[1];
        fa[tid] = a0.x * wc[0] + a0.y * wc[1] + a0.z * wc[2] + a0.w * wc[3]
                + a1.x * wc[4] + a1.y * wc[5] + a1.z * wc[6] + a1.w * wc[7];
        fm[tid] = m0.x * wc[0] + m0.y * wc[1] + m0.z * wc[2] + m0.w * wc[3]
                + m1.x * wc[4] + m1.y * wc[5] + m1.z * wc[6] + m1.w * wc[7];
    }
    __syncthreads();

    {   // first matvec: j = tid&127; avg branch (tid<128) or max branch
        const int j = tid & 127;
        const float* f = (tid < 128) ? fa : fm;     // wave-uniform
        const v4f* w1r = (const v4f*)(w1 + j * 256);
        float sacc = 0.f;
#pragma unroll 4
        for (int k4 = 0; k4 < 64; ++k4) {
            const v4f w = w1r[k4];
            sacc += w.x * f[k4 * 4 + 0] + w.y * f[k4 * 4 + 1]
                  + w.z * f[k4 * 4 + 2] + w.w * f[k4 * 4 + 3];
        }
        if (tid < 128) ha[j] = fmaxf(sacc, 0.f);
        else           hb[j] = fmaxf(sacc, 0.f);
    }
    __syncthreads();

    {   // second matvec + sigmoid + 8-way repeat; k = tid
        const v4f* w2r = (const v4f*)(w2 + tid * 128);
        float sacc = 0.f;
#pragma unroll 4
        for (int j4 = 0; j4 < 32; ++j4) {
            const v4f w = w2r[j4];
            sacc += w.x * (ha[j4 * 4 + 0] + hb[j4 * 4 + 0])
                  + w.y * (ha[j4 * 4 + 1] + hb[j4 * 4 + 1])
                  + w.z * (ha[j4 * 4 + 2] + hb[j4 * 4 + 2])
                  + w.w * (ha[j4 * 4 + 3] + hb[j4 * 4 + 3]);
        }
        const float y = 1.0f / (1.0f + expf(-sacc));
        const float4 v = make_float4(y, y, y, y);
        float4* o4 = (float4*)(out + b * 2048 + tid * 8);
        o4[0] = v;
        o4[1] = v;
    }
}

extern "C" void kernel_launch(void* const* d_in, const int* in_sizes, int n_in,
                              void* d_out, int out_size, void* d_ws, size_t ws_size,
                              hipStream_t stream) {
    const float* x    = (const float*)d_in[0];   // [16,2048,64,64]
    const float* w_ch = (const float*)d_in[1];   // [8]
    const float* w1   = (const float*)d_in[2];   // [128,256]
    const float* w2   = (const float*)d_in[3];   // [256,128]
    float* out = (float*)d_out;                  // [16,2048] (as [B,C,1,1])

    float* mean_ws = (float*)d_ws;               // 32768 floats
    float* max_ws  = mean_ws + 32768;            // 32768 floats

    pool_kernel<<<2048, 256, 0, stream>>>(x, mean_ws, max_ws);
    se_kernel<<<16, 256, 0, stream>>>(mean_ws, max_ws, w_ch, w1, w2, out);
}

// Round 8
// 99.310 us; speedup vs baseline: 5.3378x; 1.1259x over previous
//
#include <hip/hip_runtime.h>
#include <math.h>

typedef float v4f __attribute__((ext_vector_type(4)));

// x: [B=16, C=2048, H=64, W=64] fp32. H*W = 4096 contiguous floats per channel.
// Persistent pool kernel: 2048 blocks x 256 threads (4 waves/block -> 8192 waves).
// Each wave reduces 4 consecutive channels; per channel 2 batches of 8 float4
// loads (keeps live-load VGPRs at 32 -> total < 64 -> 8 waves/SIMD occupancy).
// Pure-shuffle wave reduce, no LDS, no barriers. Nontemporal loads (streaming,
// x is 512MB > L3). [R2 config: measured 99.3 us — best of 7 variants; deeper
// ILP (R1), launch_bounds pin (R3), manual dbuf pipeline (R5), channel-parallel
// (R6), and counter-fused SE (R4) all regressed.]
__global__ __launch_bounds__(256) void pool_kernel(const float* __restrict__ x,
                                                   float* __restrict__ mean_out,
                                                   float* __restrict__ max_out) {
    const int wave_g = (blockIdx.x << 2) + (threadIdx.x >> 6);   // 0..8191
    const int lane = threadIdx.x & 63;

#pragma unroll 1
    for (int i = 0; i < 4; ++i) {
        const int bc = (wave_g << 2) + i;                        // 0..32767
        const v4f* p4 = (const v4f*)(x + (size_t)bc * 4096);

        float s = 0.f;
        float m = -INFINITY;
#pragma unroll 1
        for (int batch = 0; batch < 2; ++batch) {
            v4f v[8];
#pragma unroll
            for (int j = 0; j < 8; ++j)
                v[j] = __builtin_nontemporal_load(&p4[lane + (batch * 8 + j) * 64]);
#pragma unroll
            for (int j = 0; j < 8; ++j) {
                s += (v[j].x + v[j].y) + (v[j].z + v[j].w);
                m = fmaxf(m, fmaxf(fmaxf(v[j].x, v[j].y), fmaxf(v[j].z, v[j].w)));
            }
        }
        // wave64 butterfly reduce (pure shuffles)
#pragma unroll
        for (int off = 32; off > 0; off >>= 1) {
            s += __shfl_down(s, off, 64);
            m = fmaxf(m, __shfl_down(m, off, 64));
        }
        if (lane == 0) {
            mean_out[bc] = s * (1.0f / 4096.0f);
            max_out[bc]  = m;
        }
    }
}

// Kernel 2: SE branch on [B, K=256] with Kr=128. One block per batch element.
// f[k]   = sum_o pooled[b][k*8+o] * w_ch[o]
// h[j]   = relu(<f_avg, w1[j]>) + relu(<f_max, w1[j]>)   (w2 linear -> sum ok)
// y[k]   = sigmoid(<h, w2[k]>)
// out[b][k*8+o] = y[k]
__global__ __launch_bounds__(256) void se_kernel(const float* __restrict__ mean_in,
                                                 const float* __restrict__ max_in,
                                                 const float* __restrict__ w_ch,
                                                 const float* __restrict__ w1,
                                                 const float* __restrict__ w2,
                                                 float* __restrict__ out) {
    const int b = blockIdx.x;        // 0..15
    const int tid = threadIdx.x;     // 0..255

    __shared__ float fa[256];
    __shared__ float fm[256];
    __shared__ float hs[128];
    __shared__ float wc[8];
    if (tid < 8) wc[tid] = w_ch[tid];
    __syncthreads();

    {   // orientation contraction: each thread owns one k
        const float* pa = mean_in + b * 2048 + tid * 8;
        const float* pm = max_in  + b * 2048 + tid * 8;
        float sa = 0.f, sx = 0.f;
#pragma unroll
        for (int o = 0; o < 8; ++o) {
            sa += pa[o] * wc[o];
            sx += pm[o] * wc[o];
        }
        fa[tid] = sa;
        fm[tid] = sx;
    }
    __syncthreads();

    if (tid < 128) {                 // first matvec, both branches share w1 read
        const float* w1r = w1 + tid * 256;
        float sa = 0.f, sx = 0.f;
        for (int k = 0; k < 256; ++k) {
            float w = w1r[k];
            sa += fa[k] * w;
            sx += fm[k] * w;
        }
        hs[tid] = fmaxf(sa, 0.f) + fmaxf(sx, 0.f);
    }
    __syncthreads();

    {   // second matvec + sigmoid + 8-way repeat
        const float* w2r = w2 + tid * 128;
        float s = 0.f;
        for (int j = 0; j < 128; ++j) s += hs[j] * w2r[j];
        float y = 1.0f / (1.0f + expf(-s));
        float4 v = make_float4(y, y, y, y);
        float4* o4 = (float4*)(out + b * 2048 + tid * 8);
        o4[0] = v;
        o4[1] = v;
    }
}

extern "C" void kernel_launch(void* const* d_in, const int* in_sizes, int n_in,
                              void* d_out, int out_size, void* d_ws, size_t ws_size,
                              hipStream_t stream) {
    const float* x    = (const float*)d_in[0];   // [16,2048,64,64]
    const float* w_ch = (const float*)d_in[1];   // [8]
    const float* w1   = (const float*)d_in[2];   // [128,256]
    const float* w2   = (const float*)d_in[3];   // [256,128]
    float* out = (float*)d_out;                  // [16,2048] (as [B,C,1,1])

    float* mean_ws = (float*)d_ws;               // 32768 floats
    float* max_ws  = mean_ws + 32768;            // 32768 floats

    pool_kernel<<<2048, 256, 0, stream>>>(x, mean_ws, max_ws);
    se_kernel<<<16, 256, 0, stream>>>(mean_ws, max_ws, w_ch, w1, w2, out);
}